// Round 1
// baseline (7401.963 us; speedup 1.0000x reference)
//
#include <hip/hip_runtime.h>
#include <math.h>

// AgentFormer scene decoder, incremental (KV-cached) formulation.
// A=128 agents, D=256, 8 heads x 32, 2 layers, MLP=1024, PRED_LEN=12, MEM=1024.

#define AGENTS 128
#define DIM 256
#define NHEADS 8
#define DHEAD 32
#define MEM_LEN 1024
#define MLP_DIM 1024
#define PRED 12
#define MAXS (PRED * AGENTS)   // 1536 max self-attn keys

// ---------------------------------------------------------------------------
// GEMM: C[M,N] = A[M,K] @ W[N,K]^T + bias[N]
// Block: 256 threads computes 16 rows x 64 cols. Grid (M/16, N/64).
// EPI: 0 = none, 1 = relu, 2 = add sinusoid PE (time=step, agent=row)
// ---------------------------------------------------------------------------
template <int EPI>
__device__ __forceinline__ void gemm_body(
    const float* __restrict__ Am, const float* __restrict__ W,
    const float* __restrict__ bias, float* __restrict__ C,
    int N, int K, int step)
{
  __shared__ float As[16][64];
  __shared__ float Ws[64][65];   // +1 pad: conflict-free column reads
  const int row0 = blockIdx.x * 16;
  const int col0 = blockIdx.y * 64;
  const int tid = threadIdx.x;
  const int col = tid & 63;
  const int rg  = tid >> 6;      // 0..3
  float acc[4] = {0.f, 0.f, 0.f, 0.f};

  for (int k0 = 0; k0 < K; k0 += 64) {
#pragma unroll
    for (int i = 0; i < 4; ++i) {
      int rr = rg + i * 4;
      int kk = k0 + col;
      As[rr][col] = (kk < K) ? Am[(row0 + rr) * K + kk] : 0.f;
    }
#pragma unroll
    for (int i = 0; i < 16; ++i) {
      int wr = rg + i * 4;
      int kk = k0 + col;
      Ws[wr][col] = (kk < K) ? W[(col0 + wr) * K + kk] : 0.f;
    }
    __syncthreads();
#pragma unroll 16
    for (int k = 0; k < 64; ++k) {
      float wv = Ws[col][k];
#pragma unroll
      for (int r = 0; r < 4; ++r)
        acc[r] += As[rg + 4 * r][k] * wv;   // As row broadcast within wave
    }
    __syncthreads();
  }

#pragma unroll
  for (int r = 0; r < 4; ++r) {
    int row = row0 + rg + 4 * r;
    int cc  = col0 + col;
    float v = acc[r] + bias[cc];
    if (EPI == 1) v = fmaxf(v, 0.f);
    if (EPI == 2) {
      // pe[t, c]: p = c/2, div = exp(2p * -ln(10000)/256); even->sin, odd->cos
      int p = cc >> 1;
      float dv = expf((float)(2 * p) * (-9.210340371976184f / 256.0f));
      float at = (float)step * dv;
      float aa = (float)row * dv;   // row == agent index (M=128)
      v += ((cc & 1) ? cosf(at) : sinf(at)) + ((cc & 1) ? cosf(aa) : sinf(aa));
    }
    C[row * N + cc] = v;
  }
}

template <int EPI>
__global__ __launch_bounds__(256) void gemm_k(
    const float* __restrict__ Am, const float* __restrict__ W,
    const float* __restrict__ bias, float* __restrict__ C,
    int N, int K, int step)
{
  gemm_body<EPI>(Am, W, bias, C, N, K, step);
}

// QKV in one launch: blockIdx.z selects projection
__global__ __launch_bounds__(256) void gemm_qkv_k(
    const float* __restrict__ Am,
    const float* __restrict__ Wq, const float* __restrict__ bq, float* __restrict__ Cq,
    const float* __restrict__ Wk, const float* __restrict__ bk, float* __restrict__ Ck,
    const float* __restrict__ Wv, const float* __restrict__ bv, float* __restrict__ Cv,
    int N, int K)
{
  const float* W; const float* b; float* C;
  if (blockIdx.z == 0)      { W = Wq; b = bq; C = Cq; }
  else if (blockIdx.z == 1) { W = Wk; b = bk; C = Ck; }
  else                      { W = Wv; b = bv; C = Cv; }
  gemm_body<0>(Am, W, b, C, N, K, 0);
}

// ---------------------------------------------------------------------------
// Attention for the newest 128 query tokens over S cached K/V rows.
// Queries are at the newest time => causal mask never triggers; only the
// tiled agent_mask addend applies: mask[i, j & 127].
// Block per query row i (grid=128). 256 threads = 8 heads x 32 lanes.
// ---------------------------------------------------------------------------
__global__ __launch_bounds__(256) void attn_kernel(
    const float* __restrict__ Q, const float* __restrict__ Kc,
    const float* __restrict__ Vc, const float* __restrict__ mask,
    float* __restrict__ O, int S)
{
  __shared__ float sc[NHEADS][MAXS];
  __shared__ float qs[DIM];
  const int i = blockIdx.x;
  const int tid = threadIdx.x;
  const int h = tid >> 5;
  const int lane = tid & 31;

  qs[tid] = Q[i * DIM + tid];
  __syncthreads();

  const float scale = 0.17677669529663687f;  // 1/sqrt(32)
  float lmax = -1e30f;
  for (int j = lane; j < S; j += 32) {
    const float* kr = Kc + j * DIM + h * DHEAD;
    float d = 0.f;
#pragma unroll
    for (int e = 0; e < DHEAD; ++e) d += qs[h * DHEAD + e] * kr[e];
    d = d * scale + mask[i * AGENTS + (j & (AGENTS - 1))];
    sc[h][j] = d;
    lmax = fmaxf(lmax, d);
  }
#pragma unroll
  for (int o = 16; o > 0; o >>= 1) lmax = fmaxf(lmax, __shfl_xor(lmax, o, 32));

  float lsum = 0.f;
  for (int j = lane; j < S; j += 32) {
    float e = expf(sc[h][j] - lmax);
    sc[h][j] = e;
    lsum += e;
  }
#pragma unroll
  for (int o = 16; o > 0; o >>= 1) lsum += __shfl_xor(lsum, o, 32);
  const float inv = 1.0f / lsum;

  // out[h, lane] = sum_j w_j * V[j, h*32+lane]; Vc reads coalesced across tid
  float acc = 0.f;
  for (int j = 0; j < S; ++j)
    acc += sc[h][j] * Vc[j * DIM + tid];
  O[i * DIM + tid] = acc * inv;
}

// ---------------------------------------------------------------------------
// x = LayerNorm(x + r) * g + b   (block per row, 256 threads)
// ---------------------------------------------------------------------------
__global__ __launch_bounds__(256) void add_ln_kernel(
    float* __restrict__ x, const float* __restrict__ r,
    const float* __restrict__ g, const float* __restrict__ b)
{
  __shared__ float sm[4];
  const int i = blockIdx.x, t = threadIdx.x;
  float v = x[i * DIM + t] + r[i * DIM + t];

  float s = v;
#pragma unroll
  for (int o = 32; o > 0; o >>= 1) s += __shfl_xor(s, o, 64);
  if ((t & 63) == 0) sm[t >> 6] = s;
  __syncthreads();
  const float mean = (sm[0] + sm[1] + sm[2] + sm[3]) * (1.0f / DIM);
  __syncthreads();

  const float d = v - mean;
  float s2 = d * d;
#pragma unroll
  for (int o = 32; o > 0; o >>= 1) s2 += __shfl_xor(s2, o, 64);
  if ((t & 63) == 0) sm[t >> 6] = s2;
  __syncthreads();
  const float var = (sm[0] + sm[1] + sm[2] + sm[3]) * (1.0f / DIM);

  x[i * DIM + t] = d * rsqrtf(var + 1e-5f) * g[t] + b[t];
}

// feat[i, 0:2] = scene_pos[i], feat[i, 2:130] = decoder_state[i]
__global__ void build_feat(const float* __restrict__ sp,
                           const float* __restrict__ ds,
                           float* __restrict__ feat)
{
  int idx = blockIdx.x * 256 + threadIdx.x;
  if (idx >= AGENTS * 130) return;
  int i = idx / 130, j = idx - i * 130;
  feat[idx] = (j < 2) ? sp[i * 2 + j] : ds[i * 128 + (j - 2)];
}

// rel = x @ out_W^T + out_b; out[s] = rel; scene_pos += rel. One block, 256 thr.
__global__ __launch_bounds__(256) void out_step(
    const float* __restrict__ x, const float* __restrict__ oW,
    const float* __restrict__ ob, float* __restrict__ out,
    float* __restrict__ sp, int s)
{
  const int t = threadIdx.x;
  const int i = t >> 1, j = t & 1;
  float acc = 0.f;
  for (int k = 0; k < DIM; ++k) acc += x[i * DIM + k] * oW[j * DIM + k];
  acc += ob[j];
  out[(s * AGENTS + i) * 2 + j] = acc;
  sp[i * 2 + j] += acc;
}

// ---------------------------------------------------------------------------
extern "C" void kernel_launch(void* const* d_in, const int* in_sizes, int n_in,
                              void* d_out, int out_size, void* d_ws, size_t ws_size,
                              hipStream_t stream)
{
  const float* last_pos      = (const float*)d_in[0];
  const float* decoder_state = (const float*)d_in[1];
  const float* memory        = (const float*)d_in[2];
  const float* agent_mask    = (const float*)d_in[3];
  const float* in_W  = (const float*)d_in[4];
  const float* in_b  = (const float*)d_in[5];
  const float* out_W = (const float*)d_in[6];
  const float* out_b = (const float*)d_in[7];
  const float* sa_Wq = (const float*)d_in[8];
  const float* sa_bq = (const float*)d_in[9];
  const float* sa_Wk = (const float*)d_in[10];
  const float* sa_bk = (const float*)d_in[11];
  const float* sa_Wv = (const float*)d_in[12];
  const float* sa_bv = (const float*)d_in[13];
  const float* sa_Wo = (const float*)d_in[14];
  const float* sa_bo = (const float*)d_in[15];
  const float* ca_Wq = (const float*)d_in[16];
  const float* ca_bq = (const float*)d_in[17];
  const float* ca_Wk = (const float*)d_in[18];
  const float* ca_bk = (const float*)d_in[19];
  const float* ca_Wv = (const float*)d_in[20];
  const float* ca_bv = (const float*)d_in[21];
  const float* ca_Wo = (const float*)d_in[22];
  const float* ca_bo = (const float*)d_in[23];
  const float* ff_W1 = (const float*)d_in[24];
  const float* ff_b1 = (const float*)d_in[25];
  const float* ff_W2 = (const float*)d_in[26];
  const float* ff_b2 = (const float*)d_in[27];
  const float* ln1_g = (const float*)d_in[28];
  const float* ln1_b = (const float*)d_in[29];
  const float* ln2_g = (const float*)d_in[30];
  const float* ln2_b = (const float*)d_in[31];
  const float* ln3_g = (const float*)d_in[32];
  const float* ln3_b = (const float*)d_in[33];
  float* out = (float*)d_out;

  // workspace layout (fp32), ~11.6 MB total
  float* ws    = (float*)d_ws;
  float* scene = ws;                      // 256
  float* feat  = scene + 256;             // 128*130 = 16640
  float* x     = feat + 16640;            // 32768
  float* qbuf  = x + 32768;               // 32768
  float* abuf  = qbuf + 32768;            // 32768
  float* obuf  = abuf + 32768;            // 32768
  float* ffmid = obuf + 32768;            // 128*1024 = 131072
  float* saK   = ffmid + 131072;          // 2 * 1536*256 = 786432
  float* saV   = saK + 2 * MAXS * DIM;    // 786432
  float* memK  = saV + 2 * MAXS * DIM;    // 2 * 1024*256 = 524288
  float* memV  = memK + 2 * MEM_LEN * DIM;

  const dim3 blk(256);

  // Cross-attn K/V of fixed memory: compute once per layer.
  for (int l = 0; l < 2; ++l) {
    gemm_k<0><<<dim3(64, 4), blk, 0, stream>>>(
        memory, ca_Wk + l * 65536, ca_bk + l * 256, memK + l * MEM_LEN * DIM, DIM, DIM, 0);
    gemm_k<0><<<dim3(64, 4), blk, 0, stream>>>(
        memory, ca_Wv + l * 65536, ca_bv + l * 256, memV + l * MEM_LEN * DIM, DIM, DIM, 0);
  }
  hipMemcpyAsync(scene, last_pos, 256 * sizeof(float), hipMemcpyDeviceToDevice, stream);

  for (int s = 0; s < PRED; ++s) {
    build_feat<<<65, blk, 0, stream>>>(scene, decoder_state, feat);
    gemm_k<2><<<dim3(8, 4), blk, 0, stream>>>(feat, in_W, in_b, x, DIM, 130, s);

    for (int l = 0; l < 2; ++l) {
      // self-attn: QKV (K,V written straight into the cache at time s)
      gemm_qkv_k<<<dim3(8, 4, 3), blk, 0, stream>>>(x,
          sa_Wq + l * 65536, sa_bq + l * 256, qbuf,
          sa_Wk + l * 65536, sa_bk + l * 256, saK + l * MAXS * DIM + s * AGENTS * DIM,
          sa_Wv + l * 65536, sa_bv + l * 256, saV + l * MAXS * DIM + s * AGENTS * DIM,
          DIM, DIM);
      attn_kernel<<<AGENTS, blk, 0, stream>>>(
          qbuf, saK + l * MAXS * DIM, saV + l * MAXS * DIM, agent_mask, abuf,
          (s + 1) * AGENTS);
      gemm_k<0><<<dim3(8, 4), blk, 0, stream>>>(
          abuf, sa_Wo + l * 65536, sa_bo + l * 256, obuf, DIM, DIM, 0);
      add_ln_kernel<<<AGENTS, blk, 0, stream>>>(x, obuf, ln1_g + l * 256, ln1_b + l * 256);

      // cross-attn over precomputed memory K/V
      gemm_k<0><<<dim3(8, 4), blk, 0, stream>>>(
          x, ca_Wq + l * 65536, ca_bq + l * 256, qbuf, DIM, DIM, 0);
      attn_kernel<<<AGENTS, blk, 0, stream>>>(
          qbuf, memK + l * MEM_LEN * DIM, memV + l * MEM_LEN * DIM, agent_mask, abuf,
          MEM_LEN);
      gemm_k<0><<<dim3(8, 4), blk, 0, stream>>>(
          abuf, ca_Wo + l * 65536, ca_bo + l * 256, obuf, DIM, DIM, 0);
      add_ln_kernel<<<AGENTS, blk, 0, stream>>>(x, obuf, ln2_g + l * 256, ln2_b + l * 256);

      // feed-forward
      gemm_k<1><<<dim3(8, 16), blk, 0, stream>>>(
          x, ff_W1 + l * 262144, ff_b1 + l * 1024, ffmid, MLP_DIM, DIM, 0);
      gemm_k<0><<<dim3(8, 4), blk, 0, stream>>>(
          ffmid, ff_W2 + l * 262144, ff_b2 + l * 256, obuf, DIM, MLP_DIM, 0);
      add_ln_kernel<<<AGENTS, blk, 0, stream>>>(x, obuf, ln3_g + l * 256, ln3_b + l * 256);
    }

    out_step<<<1, blk, 0, stream>>>(x, out_W, out_b, out, scene, s);
  }
}

// Round 2
// 4108.269 us; speedup vs baseline: 1.8017x; 1.8017x over previous
//
#include <hip/hip_runtime.h>
#include <math.h>

#define AGENTS 128
#define DIM 256
#define MEM_LEN 1024
#define MLP_DIM 1024
#define PRED 12
#define MAXS (PRED * AGENTS)   // 1536

typedef __attribute__((ext_vector_type(8))) short short8;
typedef __attribute__((ext_vector_type(4))) float f32x4;

__device__ __forceinline__ unsigned short f2bf(float f) {
  union { float f; unsigned u; } v; v.f = f;
  unsigned r = v.u + 0x7fffu + ((v.u >> 16) & 1u);   // RNE
  return (unsigned short)(r >> 16);
}

// A-fragment: 8 consecutive fp32 -> bf16. p must be 32B-aligned.
__device__ __forceinline__ short8 afrag_g(const float* __restrict__ p) {
  float4 a = ((const float4*)p)[0];
  float4 b = ((const float4*)p)[1];
  short8 r;
  r[0] = (short)f2bf(a.x); r[1] = (short)f2bf(a.y);
  r[2] = (short)f2bf(a.z); r[3] = (short)f2bf(a.w);
  r[4] = (short)f2bf(b.x); r[5] = (short)f2bf(b.y);
  r[6] = (short)f2bf(b.z); r[7] = (short)f2bf(b.w);
  return r;
}

// ---------------------------------------------------------------------------
// Plain MFMA GEMM body: 16 rows x 256 cols per block (4 waves x 4 n-tiles).
// A fp32 [M][K] row-major; W bf16-bits [N][K] row-major. C = A*W^T.
// frag layout (16x16x32): lane l: A[l&15][ (l>>4)*8 + j ], B = W[l&15][same k]
// C: col = lane&15, row = (lane>>4)*4 + reg.
// ---------------------------------------------------------------------------
#define MFMA(a, b, c) __builtin_amdgcn_mfma_f32_16x16x32_bf16(a, b, c, 0, 0, 0)

// ---------------------------------------------------------------------------
// QKV (and generic triple) GEMM: grid (8,1,3), M=128, K=256.
// ---------------------------------------------------------------------------
__global__ __launch_bounds__(256) void qkv_k(
    const float* __restrict__ x,
    const unsigned short* __restrict__ W0, const float* __restrict__ b0, float* __restrict__ o0,
    const unsigned short* __restrict__ W1, const float* __restrict__ b1, float* __restrict__ o1,
    const unsigned short* __restrict__ W2, const float* __restrict__ b2, float* __restrict__ o2)
{
  const unsigned short* W; const float* b; float* o;
  if (blockIdx.z == 0)      { W = W0; b = b0; o = o0; }
  else if (blockIdx.z == 1) { W = W1; b = b1; o = o1; }
  else                      { W = W2; b = b2; o = o2; }
  const int tid = threadIdx.x, l = tid & 63, w = tid >> 6;
  const int c15 = l & 15, klane = (l >> 4) * 8;
  const int row0 = blockIdx.x * 16;
  f32x4 acc[4] = {};
  const float* arow = x + (row0 + c15) * 256 + klane;
  const unsigned short* wp = W + (w * 64 + c15) * 256 + klane;
  for (int k0 = 0; k0 < 256; k0 += 32) {
    short8 af = afrag_g(arow + k0);
#pragma unroll
    for (int t = 0; t < 4; ++t) {
      short8 bf = *(const short8*)(wp + t * 16 * 256 + k0);
      acc[t] = MFMA(af, bf, acc[t]);
    }
  }
  const int r0 = (l >> 4) * 4;
#pragma unroll
  for (int t = 0; t < 4; ++t) {
    int c = w * 64 + t * 16 + c15;
    float bb = b[c];
#pragma unroll
    for (int r = 0; r < 4; ++r)
      o[(row0 + r0 + r) * DIM + c] = acc[t][r] + bb;
  }
}

// memory K/V precompute: grid (64,1,4); z = l*2 + (0=K,1=V); M=1024, K=256.
__global__ __launch_bounds__(256) void memkv_k(
    const float* __restrict__ mem, const unsigned short* __restrict__ dxd,
    const float* __restrict__ bk, const float* __restrict__ bvv,
    float* __restrict__ memK, float* __restrict__ memV)
{
  const int z = blockIdx.z, li = z >> 1, which = z & 1;
  const unsigned short* W = dxd + (5 + which) * 131072 + li * 65536;  // ca_Wk=5, ca_Wv=6
  const float* b = (which ? bvv : bk) + li * 256;
  float* o = (which ? memV : memK) + li * MEM_LEN * DIM;
  const int tid = threadIdx.x, l = tid & 63, w = tid >> 6;
  const int c15 = l & 15, klane = (l >> 4) * 8;
  const int row0 = blockIdx.x * 16;
  f32x4 acc[4] = {};
  const float* arow = mem + (row0 + c15) * 256 + klane;
  const unsigned short* wp = W + (w * 64 + c15) * 256 + klane;
  for (int k0 = 0; k0 < 256; k0 += 32) {
    short8 af = afrag_g(arow + k0);
#pragma unroll
    for (int t = 0; t < 4; ++t) {
      short8 bf = *(const short8*)(wp + t * 16 * 256 + k0);
      acc[t] = MFMA(af, bf, acc[t]);
    }
  }
  const int r0 = (l >> 4) * 4;
#pragma unroll
  for (int t = 0; t < 4; ++t) {
    int c = w * 64 + t * 16 + c15;
    float bb = b[c];
#pragma unroll
    for (int r = 0; r < 4; ++r)
      o[(row0 + r0 + r) * DIM + c] = acc[t][r] + bb;
  }
}

// FF1 with ReLU: grid (8,4); N=1024, K=256.
__global__ __launch_bounds__(256) void ff1_k(
    const float* __restrict__ x, const unsigned short* __restrict__ W,
    const float* __restrict__ b, float* __restrict__ mid)
{
  const int tid = threadIdx.x, l = tid & 63, w = tid >> 6;
  const int c15 = l & 15, klane = (l >> 4) * 8;
  const int row0 = blockIdx.x * 16, colbase = blockIdx.y * 256;
  f32x4 acc[4] = {};
  const float* arow = x + (row0 + c15) * 256 + klane;
  const unsigned short* wp = W + (colbase + w * 64 + c15) * 256 + klane;
  for (int k0 = 0; k0 < 256; k0 += 32) {
    short8 af = afrag_g(arow + k0);
#pragma unroll
    for (int t = 0; t < 4; ++t) {
      short8 bf = *(const short8*)(wp + t * 16 * 256 + k0);
      acc[t] = MFMA(af, bf, acc[t]);
    }
  }
  const int r0 = (l >> 4) * 4;
#pragma unroll
  for (int t = 0; t < 4; ++t) {
    int c = colbase + w * 64 + t * 16 + c15;
    float bb = b[c];
#pragma unroll
    for (int r = 0; r < 4; ++r)
      mid[(row0 + r0 + r) * MLP_DIM + c] = fmaxf(acc[t][r] + bb, 0.f);
  }
}

// ---------------------------------------------------------------------------
// Output projection + residual + LayerNorm, optionally fused next-Q GEMM
// (FUSEQ) or final out-projection + scene update (OUTP). Grid (8).
// ---------------------------------------------------------------------------
template <bool FUSEQ, bool OUTP>
__global__ __launch_bounds__(256) void oln_k(
    const float* __restrict__ Ain, const unsigned short* __restrict__ Wo,
    const float* __restrict__ bo, int K,
    const float* __restrict__ resid, const float* __restrict__ g,
    const float* __restrict__ bv, float* __restrict__ xout,
    const unsigned short* __restrict__ Wq, const float* __restrict__ bq,
    float* __restrict__ qout,
    const float* __restrict__ outW, const float* __restrict__ outB,
    float* __restrict__ outbuf, float* __restrict__ scene, int step)
{
  __shared__ float sx[16][264];
  const int tid = threadIdx.x, l = tid & 63, w = tid >> 6;
  const int c15 = l & 15, klane = (l >> 4) * 8;
  const int row0 = blockIdx.x * 16;
  const int r0 = (l >> 4) * 4;

  f32x4 acc[4] = {};
  {
    const float* arow = Ain + (row0 + c15) * K + klane;
    const unsigned short* wp = Wo + (w * 64 + c15) * K + klane;
    for (int k0 = 0; k0 < K; k0 += 32) {
      short8 af = afrag_g(arow + k0);
#pragma unroll
      for (int t = 0; t < 4; ++t) {
        short8 bf = *(const short8*)(wp + t * 16 * K + k0);
        acc[t] = MFMA(af, bf, acc[t]);
      }
    }
  }
#pragma unroll
  for (int t = 0; t < 4; ++t) {
    int c = w * 64 + t * 16 + c15;
    float bb = bo[c];
#pragma unroll
    for (int r = 0; r < 4; ++r)
      sx[r0 + r][c] = acc[t][r] + bb + resid[(row0 + r0 + r) * DIM + c];
  }
  __syncthreads();

  // LayerNorm: wave w handles rows 4w..4w+3; 64 lanes x 4 elems each.
#pragma unroll
  for (int rr = 0; rr < 4; ++rr) {
    int row = w * 4 + rr;
    float4 v = *(const float4*)&sx[row][l * 4];
    float s = v.x + v.y + v.z + v.w;
#pragma unroll
    for (int o = 32; o > 0; o >>= 1) s += __shfl_xor(s, o, 64);
    float mean = s * (1.0f / 256.0f);
    float dx = v.x - mean, dy = v.y - mean, dz = v.z - mean, dw = v.w - mean;
    float s2 = dx * dx + dy * dy + dz * dz + dw * dw;
#pragma unroll
    for (int o = 32; o > 0; o >>= 1) s2 += __shfl_xor(s2, o, 64);
    float rstd = rsqrtf(s2 * (1.0f / 256.0f) + 1e-5f);
    float4 gg = *(const float4*)&g[l * 4];
    float4 bb = *(const float4*)&bv[l * 4];
    float4 o4;
    o4.x = dx * rstd * gg.x + bb.x;
    o4.y = dy * rstd * gg.y + bb.y;
    o4.z = dz * rstd * gg.z + bb.z;
    o4.w = dw * rstd * gg.w + bb.w;
    *(float4*)&sx[row][l * 4] = o4;
    *(float4*)&xout[(row0 + row) * DIM + l * 4] = o4;
  }
  if (FUSEQ || OUTP) __syncthreads();

  if (FUSEQ) {
    f32x4 q[4] = {};
    for (int k0 = 0; k0 < 256; k0 += 32) {
      const float* sp = &sx[c15][k0 + klane];
      float4 a0 = *(const float4*)sp;
      float4 a1 = *(const float4*)(sp + 4);
      short8 af;
      af[0] = (short)f2bf(a0.x); af[1] = (short)f2bf(a0.y);
      af[2] = (short)f2bf(a0.z); af[3] = (short)f2bf(a0.w);
      af[4] = (short)f2bf(a1.x); af[5] = (short)f2bf(a1.y);
      af[6] = (short)f2bf(a1.z); af[7] = (short)f2bf(a1.w);
      const unsigned short* wp = Wq + (w * 64 + c15) * 256 + k0 + klane;
#pragma unroll
      for (int t = 0; t < 4; ++t) {
        short8 bf = *(const short8*)(wp + t * 16 * 256);
        q[t] = MFMA(af, bf, q[t]);
      }
    }
#pragma unroll
    for (int t = 0; t < 4; ++t) {
      int c = w * 64 + t * 16 + c15;
      float bb = bq[c];
#pragma unroll
      for (int r = 0; r < 4; ++r)
        qout[(row0 + r0 + r) * DIM + c] = q[t][r] + bb;
    }
  }
  if (OUTP) {
    if (tid < 32) {
      int il = tid >> 1, j = tid & 1;
      float a = 0.f;
      for (int k = 0; k < 256; ++k) a += sx[il][k] * outW[j * 256 + k];
      a += outB[j];
      int gi = row0 + il;
      outbuf[(step * AGENTS + gi) * 2 + j] = a;
      scene[gi * 2 + j] += a;
    }
  }
}

// ---------------------------------------------------------------------------
// Embed: x = [scene|ds] @ in_W^T + in_b + agentPE + timePE(step). Grid (8).
// in_Wb is [256][160] bf16, zero-padded beyond k=130.
// ---------------------------------------------------------------------------
__global__ __launch_bounds__(256) void embed_k(
    const float* __restrict__ scene, const float* __restrict__ ds,
    const unsigned short* __restrict__ inWb, const float* __restrict__ inb,
    const float* __restrict__ peA, const float* __restrict__ peT,
    float* __restrict__ x, int step)
{
  const int tid = threadIdx.x, l = tid & 63, w = tid >> 6;
  const int c15 = l & 15, klane = (l >> 4) * 8;
  const int row0 = blockIdx.x * 16;
  const int mrow = row0 + c15;
  f32x4 acc[4] = {};
  for (int k0 = 0; k0 < 160; k0 += 32) {
    short8 af;
#pragma unroll
    for (int j = 0; j < 8; ++j) {
      int kk = k0 + klane + j;
      float v = (kk < 2) ? scene[mrow * 2 + kk]
                         : ((kk < 130) ? ds[mrow * 128 + (kk - 2)] : 0.f);
      af[j] = (short)f2bf(v);
    }
    const unsigned short* wp = inWb + (w * 64 + c15) * 160 + k0 + klane;
#pragma unroll
    for (int t = 0; t < 4; ++t) {
      short8 bf = *(const short8*)(wp + t * 16 * 160);
      acc[t] = MFMA(af, bf, acc[t]);
    }
  }
  const int r0 = (l >> 4) * 4;
#pragma unroll
  for (int t = 0; t < 4; ++t) {
    int c = w * 64 + t * 16 + c15;
    float bb = inb[c] + peT[step * DIM + c];
#pragma unroll
    for (int r = 0; r < 4; ++r) {
      int row = row0 + r0 + r;
      x[row * DIM + c] = acc[t][r] + bb + peA[row * DIM + c];
    }
  }
}

// ---------------------------------------------------------------------------
// Attention: newest 128 queries over S cached K/V rows (fp32).
// Block per query row; 256 thr = 8 heads x 32 lanes.
// ---------------------------------------------------------------------------
__global__ __launch_bounds__(256) void attn_k(
    const float* __restrict__ Q, const float* __restrict__ Kc,
    const float* __restrict__ Vc, const float* __restrict__ mask,
    float* __restrict__ O, int S)
{
  __shared__ float sc[8][MAXS];
  const int i = blockIdx.x, tid = threadIdx.x;
  const int h = tid >> 5, lane = tid & 31;

  float4 q[8];
  {
    const float4* qp = (const float4*)(Q + i * DIM + h * 32);
#pragma unroll
    for (int e = 0; e < 8; ++e) q[e] = qp[e];
  }
  float mk[4];
#pragma unroll
  for (int c = 0; c < 4; ++c) mk[c] = mask[i * AGENTS + ((lane + 32 * c) & (AGENTS - 1))];

  const float scale = 0.17677669529663687f;  // 1/sqrt(32)
  float lmax = -1e30f;
  int it = 0;
  for (int j = lane; j < S; j += 32, ++it) {
    const float4* kr = (const float4*)(Kc + j * DIM + h * 32);
    float d = 0.f;
#pragma unroll
    for (int e = 0; e < 8; ++e) {
      float4 kv = kr[e];
      d += q[e].x * kv.x + q[e].y * kv.y + q[e].z * kv.z + q[e].w * kv.w;
    }
    d = d * scale + mk[it & 3];
    sc[h][j] = d;
    lmax = fmaxf(lmax, d);
  }
#pragma unroll
  for (int o = 16; o > 0; o >>= 1) lmax = fmaxf(lmax, __shfl_xor(lmax, o, 32));

  float lsum = 0.f;
  for (int j = lane; j < S; j += 32) {
    float e = expf(sc[h][j] - lmax);
    sc[h][j] = e;
    lsum += e;
  }
#pragma unroll
  for (int o = 16; o > 0; o >>= 1) lsum += __shfl_xor(lsum, o, 32);
  const float inv = 1.0f / lsum;

  float acc = 0.f;
  for (int j = 0; j < S; j += 4) {
    float4 w4 = *(const float4*)&sc[h][j];
    acc += w4.x * Vc[(j + 0) * DIM + tid] + w4.y * Vc[(j + 1) * DIM + tid] +
           w4.z * Vc[(j + 2) * DIM + tid] + w4.w * Vc[(j + 3) * DIM + tid];
  }
  O[i * DIM + tid] = acc * inv;
}

// ---------------------------------------------------------------------------
// Prologue converters / tables
// ---------------------------------------------------------------------------
__global__ void cvt8_k(const float* p0, const float* p1, const float* p2,
                       const float* p3, const float* p4, const float* p5,
                       const float* p6, const float* p7, unsigned short* dst)
{
  const float* s;
  switch (blockIdx.z) {
    case 0: s = p0; break; case 1: s = p1; break;
    case 2: s = p2; break; case 3: s = p3; break;
    case 4: s = p4; break; case 5: s = p5; break;
    case 6: s = p6; break; default: s = p7; break;
  }
  int i = blockIdx.x * 256 + threadIdx.x;
  dst[blockIdx.z * 131072 + i] = f2bf(s[i]);
}

__global__ void cvtff_k(const float* w1, const float* w2, unsigned short* dst)
{
  const float* s = blockIdx.z ? w2 : w1;
  int i = blockIdx.x * 256 + threadIdx.x;
  dst[blockIdx.z * 524288 + i] = f2bf(s[i]);
}

__global__ void cvtinw_k(const float* w, unsigned short* dst)
{
  int i = blockIdx.x * 256 + threadIdx.x;
  if (i >= 256 * 160) return;
  int n = i / 160, k = i - n * 160;
  dst[i] = (k < 130) ? f2bf(w[n * 130 + k]) : (unsigned short)0;
}

__global__ void pe_k(float* peA, float* peT)
{
  int i = blockIdx.x * 256 + threadIdx.x;
  if (i < 128 * 256) {
    int row = i >> 8, c = i & 255, p = c >> 1;
    float dv = expf((float)(2 * p) * (-9.210340371976184f / 256.f));
    float ang = (float)row * dv;
    peA[i] = (c & 1) ? cosf(ang) : sinf(ang);
  } else if (i < 140 * 256) {
    int j = i - 32768;
    int s = j >> 8, c = j & 255, p = c >> 1;
    float dv = expf((float)(2 * p) * (-9.210340371976184f / 256.f));
    float ang = (float)s * dv;
    peT[j] = (c & 1) ? cosf(ang) : sinf(ang);
  }
}

// ---------------------------------------------------------------------------
extern "C" void kernel_launch(void* const* d_in, const int* in_sizes, int n_in,
                              void* d_out, int out_size, void* d_ws, size_t ws_size,
                              hipStream_t stream)
{
  const float* last_pos      = (const float*)d_in[0];
  const float* decoder_state = (const float*)d_in[1];
  const float* memory        = (const float*)d_in[2];
  const float* agent_mask    = (const float*)d_in[3];
  const float* in_W  = (const float*)d_in[4];
  const float* in_b  = (const float*)d_in[5];
  const float* out_W = (const float*)d_in[6];
  const float* out_b = (const float*)d_in[7];
  const float* sa_Wq = (const float*)d_in[8];
  const float* sa_bq = (const float*)d_in[9];
  const float* sa_Wk = (const float*)d_in[10];
  const float* sa_bk = (const float*)d_in[11];
  const float* sa_Wv = (const float*)d_in[12];
  const float* sa_bv = (const float*)d_in[13];
  const float* sa_Wo = (const float*)d_in[14];
  const float* sa_bo = (const float*)d_in[15];
  const float* ca_Wq = (const float*)d_in[16];
  const float* ca_bq = (const float*)d_in[17];
  const float* ca_Wk = (const float*)d_in[18];
  const float* ca_bk = (const float*)d_in[19];
  const float* ca_Wv = (const float*)d_in[20];
  const float* ca_bv = (const float*)d_in[21];
  const float* ca_Wo = (const float*)d_in[22];
  const float* ca_bo = (const float*)d_in[23];
  const float* ff_W1 = (const float*)d_in[24];
  const float* ff_b1 = (const float*)d_in[25];
  const float* ff_W2 = (const float*)d_in[26];
  const float* ff_b2 = (const float*)d_in[27];
  const float* ln1_g = (const float*)d_in[28];
  const float* ln1_b = (const float*)d_in[29];
  const float* ln2_g = (const float*)d_in[30];
  const float* ln2_b = (const float*)d_in[31];
  const float* ln3_g = (const float*)d_in[32];
  const float* ln3_b = (const float*)d_in[33];
  float* out = (float*)d_out;

  // fp32 workspace
  float* ws    = (float*)d_ws;
  float* scene = ws;                       // 256
  float* x     = scene + 256;              // 32768
  float* qbuf  = x + 32768;                // 32768
  float* abuf  = qbuf + 32768;             // 32768
  float* ffmid = abuf + 32768;             // 131072
  float* saK   = ffmid + 131072;           // 2*1536*256
  float* saV   = saK + 2 * MAXS * DIM;
  float* memK  = saV + 2 * MAXS * DIM;     // 2*1024*256
  float* memV  = memK + 2 * MEM_LEN * DIM;
  float* peA   = memV + 2 * MEM_LEN * DIM; // 32768
  float* peT   = peA + 32768;              // 3072
  // bf16 weights
  unsigned short* dxdb = (unsigned short*)(peT + 3072); // 8*131072
  unsigned short* ffW1b = dxdb + 8 * 131072;            // 524288
  unsigned short* ffW2b = ffW1b + 524288;               // 524288
  unsigned short* inWb  = ffW2b + 524288;               // 40960

  const dim3 blk(256);

  // prologue: weight conversion, PE tables, memory K/V
  cvt8_k<<<dim3(512, 1, 8), blk, 0, stream>>>(sa_Wq, sa_Wk, sa_Wv, sa_Wo,
                                              ca_Wq, ca_Wk, ca_Wv, ca_Wo, dxdb);
  cvtff_k<<<dim3(2048, 1, 2), blk, 0, stream>>>(ff_W1, ff_W2, ffW1b);
  cvtinw_k<<<160, blk, 0, stream>>>(in_W, inWb);
  pe_k<<<140, blk, 0, stream>>>(peA, peT);
  memkv_k<<<dim3(64, 1, 4), blk, 0, stream>>>(memory, dxdb, ca_bk, ca_bv, memK, memV);
  hipMemcpyAsync(scene, last_pos, 256 * sizeof(float), hipMemcpyDeviceToDevice, stream);

  for (int s = 0; s < PRED; ++s) {
    embed_k<<<8, blk, 0, stream>>>(scene, decoder_state, inWb, in_b, peA, peT, x, s);

    for (int l = 0; l < 2; ++l) {
      const unsigned short* saWq = dxdb + 0 * 131072 + l * 65536;
      const unsigned short* saWk = dxdb + 1 * 131072 + l * 65536;
      const unsigned short* saWv = dxdb + 2 * 131072 + l * 65536;
      const unsigned short* saWo = dxdb + 3 * 131072 + l * 65536;
      const unsigned short* caWq = dxdb + 4 * 131072 + l * 65536;
      const unsigned short* caWo = dxdb + 7 * 131072 + l * 65536;

      qkv_k<<<dim3(8, 1, 3), blk, 0, stream>>>(x,
          saWq, sa_bq + l * 256, qbuf,
          saWk, sa_bk + l * 256, saK + l * MAXS * DIM + s * AGENTS * DIM,
          saWv, sa_bv + l * 256, saV + l * MAXS * DIM + s * AGENTS * DIM);
      attn_k<<<AGENTS, blk, 0, stream>>>(qbuf, saK + l * MAXS * DIM,
                                         saV + l * MAXS * DIM, agent_mask, abuf,
                                         (s + 1) * AGENTS);
      // SA out-proj + LN1 + fused CA-Q projection
      oln_k<true, false><<<8, blk, 0, stream>>>(
          abuf, saWo, sa_bo + l * 256, 256, x, ln1_g + l * 256, ln1_b + l * 256, x,
          caWq, ca_bq + l * 256, qbuf,
          nullptr, nullptr, nullptr, nullptr, 0);
      attn_k<<<AGENTS, blk, 0, stream>>>(qbuf, memK + l * MEM_LEN * DIM,
                                         memV + l * MEM_LEN * DIM, agent_mask, abuf,
                                         MEM_LEN);
      // CA out-proj + LN2
      oln_k<false, false><<<8, blk, 0, stream>>>(
          abuf, caWo, ca_bo + l * 256, 256, x, ln2_g + l * 256, ln2_b + l * 256, x,
          nullptr, nullptr, nullptr, nullptr, nullptr, nullptr, nullptr, 0);
      // FF
      ff1_k<<<dim3(8, 4), blk, 0, stream>>>(x, ffW1b + l * 262144, ff_b1 + l * 1024, ffmid);
      if (l == 0) {
        oln_k<false, false><<<8, blk, 0, stream>>>(
            ffmid, ffW2b + l * 262144, ff_b2 + l * 256, 1024, x,
            ln3_g + l * 256, ln3_b + l * 256, x,
            nullptr, nullptr, nullptr, nullptr, nullptr, nullptr, nullptr, 0);
      } else {
        // FF2 + LN3 + fused out-projection + scene update
        oln_k<false, true><<<8, blk, 0, stream>>>(
            ffmid, ffW2b + l * 262144, ff_b2 + l * 256, 1024, x,
            ln3_g + l * 256, ln3_b + l * 256, x,
            nullptr, nullptr, nullptr, out_W, out_b, out, scene, s);
      }
    }
  }
}